// Round 7
// baseline (1136.202 us; speedup 1.0000x reference)
//
#include <hip/hip_runtime.h>
#include <hip/hip_bf16.h>

// Problem constants (from reference)
#define N_NODES 50000
#define N_EDGES 1600000
#define D_FEAT  64

// ---------------------------------------------------------------------------
// Kernel 1: out-degree histogram (over row) + in-degree histogram (over col)
// ---------------------------------------------------------------------------
__global__ void degcnt_kernel(const int* __restrict__ row, const int* __restrict__ col,
                              int* __restrict__ degi, int* __restrict__ cnt) {
    int e = blockIdx.x * blockDim.x + threadIdx.x;
    if (e < N_EDGES) {
        atomicAdd(&degi[row[e]], 1);
        atomicAdd(&cnt[col[e]], 1);
    }
}

// ---------------------------------------------------------------------------
// Kernel 2: dis[i] = deg>0 ? rsqrt(deg) : 0
// ---------------------------------------------------------------------------
__global__ void dis_kernel(const int* __restrict__ degi, float* __restrict__ disf) {
    int i = blockIdx.x * blockDim.x + threadIdx.x;
    if (i < N_NODES) {
        int d = degi[i];
        disf[i] = (d > 0) ? rsqrtf((float)d) : 0.0f;
    }
}

// ---------------------------------------------------------------------------
// Kernel 3: exclusive scan of cnt[50000] -> offs, cursor. One block, 256 thr.
// Each thread serially sums a 196-element chunk, block-scan of partials in
// LDS (Hillis-Steele), then re-walk chunk writing running offsets.
// ---------------------------------------------------------------------------
__global__ void scan_kernel(const int* __restrict__ cnt, int* __restrict__ offs,
                            int* __restrict__ cursor) {
    __shared__ int part[256];
    const int CH = 196;                 // 256*196 = 50176 >= 50000
    int t = threadIdx.x;
    int base = t * CH;
    int s = 0;
    for (int i = 0; i < CH; ++i) {
        int idx = base + i;
        if (idx < N_NODES) s += cnt[idx];
    }
    part[t] = s;
    __syncthreads();
    // inclusive Hillis-Steele scan over 256 partials
    for (int d = 1; d < 256; d <<= 1) {
        int v = part[t];
        int add = (t >= d) ? part[t - d] : 0;
        __syncthreads();
        part[t] = v + add;
        __syncthreads();
    }
    int run = part[t] - s;              // exclusive prefix for this chunk
    for (int i = 0; i < CH; ++i) {
        int idx = base + i;
        if (idx < N_NODES) {
            offs[idx] = run;
            cursor[idx] = run;
            run += cnt[idx];
        }
    }
}

// ---------------------------------------------------------------------------
// Kernel 4: CSR fill — slot per edge grouped by target; packs (src, weight)
// ---------------------------------------------------------------------------
__global__ void fill_kernel(const int* __restrict__ row, const int* __restrict__ col,
                            const float* __restrict__ disf,
                            int* __restrict__ cursor, int2* __restrict__ edat) {
    int e = blockIdx.x * blockDim.x + threadIdx.x;
    if (e < N_EDGES) {
        int r = row[e];
        int c = col[e];
        float w = -(disf[r] * disf[c]);
        int p = atomicAdd(&cursor[c], 1);
        edat[p] = make_int2(r, __float_as_int(w));
    }
}

// ---------------------------------------------------------------------------
// Kernel 5: gather prop — out[n][j] = sum_{e in in(n)} w_e * z[src_e][j]
// One wave (64 lanes) per node, lane = feature. No atomics; fully overwrites
// out, so no memset needed.
// ---------------------------------------------------------------------------
__global__ void gather_kernel(const int* __restrict__ offs, const int* __restrict__ cnt,
                              const int2* __restrict__ edat,
                              const float* __restrict__ z, float* __restrict__ out) {
    int t = threadIdx.x;
    int wv = t >> 6;            // wave within block: 0..3
    int j  = t & 63;            // feature
    int n  = blockIdx.x * 4 + wv;   // 12500 * 4 = 50000 exact
    int start = offs[n];
    int end   = start + cnt[n];
    float acc = 0.0f;
    for (int k = start; k < end; ++k) {
        int2 d = edat[k];
        acc += __int_as_float(d.y) * z[(size_t)d.x * D_FEAT + j];
    }
    out[(size_t)n * D_FEAT + j] = acc;
}

// ---------------------------------------------------------------------------
// Kernel 6: fused Chebyshev combine + bias + relu
//   h[n] = relu( z[n]@(W0-W2) + t1[n]@W1 + 2*t2[n]@W2 + b )
// (Tx2 = 2*t2 - z;  out = z@W0 + t1@W1 + Tx2@W2)
// Block: 256 threads = 4 nodes x 64 output features. In-place safe (LDS
// staging of own rows before any write).
// ---------------------------------------------------------------------------
__global__ void cheb_fused_kernel(const float* __restrict__ z, const float* __restrict__ t1,
                                  const float* __restrict__ t2,
                                  const float* __restrict__ W, const float* __restrict__ b,
                                  float* __restrict__ h) {
    __shared__ float zs[4][D_FEAT];
    __shared__ float t1s[4][D_FEAT];
    __shared__ float t2s[4][D_FEAT];
    int t  = threadIdx.x;
    int nl = t >> 6;
    int j  = t & 63;
    int node = blockIdx.x * 4 + nl;
    size_t base = (size_t)node * D_FEAT + j;
    zs[nl][j]  = z[base];
    t1s[nl][j] = t1[base];
    t2s[nl][j] = t2[base];
    __syncthreads();

    const float* W0 = W;
    const float* W1 = W + D_FEAT * D_FEAT;
    const float* W2 = W + 2 * D_FEAT * D_FEAT;

    float acc = b[j];
    #pragma unroll
    for (int k = 0; k < D_FEAT; ++k) {
        float w2 = W2[k * D_FEAT + j];
        acc += zs[nl][k]  * (W0[k * D_FEAT + j] - w2);
        acc += t1s[nl][k] * W1[k * D_FEAT + j];
        acc += 2.0f * t2s[nl][k] * w2;
    }
    h[base] = fmaxf(acc, 0.0f);
}

// ---------------------------------------------------------------------------
// Kernel 7: logits[n] = h[n] @ Wlin + blin  (64 -> 2), float32 out
// ---------------------------------------------------------------------------
__global__ void logits_kernel(const float* __restrict__ h, const float* __restrict__ Wlin,
                              const float* __restrict__ blin,
                              float* __restrict__ out) {
    int n = blockIdx.x * blockDim.x + threadIdx.x;
    if (n >= N_NODES) return;
    float a0 = blin[0];
    float a1 = blin[1];
    const float* hr = h + (size_t)n * D_FEAT;
    #pragma unroll
    for (int j = 0; j < D_FEAT; ++j) {
        float v = hr[j];
        a0 += v * Wlin[j * 2 + 0];
        a1 += v * Wlin[j * 2 + 1];
    }
    out[n * 2 + 0] = a0;
    out[n * 2 + 1] = a1;
}

// ---------------------------------------------------------------------------
// Kernel 8: echo edge_index into output (as float32)
// ---------------------------------------------------------------------------
__global__ void edgecopy_kernel(const int* __restrict__ ei, float* __restrict__ out) {
    int t = blockIdx.x * blockDim.x + threadIdx.x;
    if (t < 2 * N_EDGES) {
        out[t] = (float)ei[t];
    }
}

// ---------------------------------------------------------------------------
extern "C" void kernel_launch(void* const* d_in, const int* in_sizes, int n_in,
                              void* d_out, int out_size, void* d_ws, size_t ws_size,
                              hipStream_t stream) {
    const float* x    = (const float*)d_in[0];
    const int*   ei   = (const int*)d_in[1];
    const float* W1   = (const float*)d_in[2];
    const float* b1   = (const float*)d_in[3];
    const float* W2   = (const float*)d_in[4];
    const float* b2   = (const float*)d_in[5];
    const float* Wlin = (const float*)d_in[6];
    const float* blin = (const float*)d_in[7];
    float* out = (float*)d_out;      // float32 output buffer (logits f32; edge echo as f32)
    float* ws  = (float*)d_ws;

    const int* row = ei;             // edge_index[0] = source
    const int* col = ei + N_EDGES;   // edge_index[1] = target

    // workspace layout (4-byte units); total ~52.2 MB
    int*   degi   = (int*)ws;                     // [50176]
    float* disf   = ws + 50176;                   // [50176]
    int*   cnt    = (int*)(ws + 100352);          // [50176]
    int*   offs   = (int*)(ws + 150528);          // [50176]
    int*   cursor = (int*)(ws + 200704);          // [50176]
    int2*  edat   = (int2*)(ws + 250880);         // [1600000] (8B-aligned)
    float* T1     = ws + 3450880;                 // [3.2M]
    float* T2     = ws + 6650880;                 // [3.2M]
    float* H      = ws + 9850880;                 // [3.2M]

    // --- CSR build ---
    hipMemsetAsync(degi, 0, N_NODES * sizeof(int), stream);
    hipMemsetAsync(cnt,  0, N_NODES * sizeof(int), stream);
    degcnt_kernel<<<N_EDGES / 256, 256, 0, stream>>>(row, col, degi, cnt);
    dis_kernel<<<(N_NODES + 255) / 256, 256, 0, stream>>>(degi, disf);
    scan_kernel<<<1, 256, 0, stream>>>(cnt, offs, cursor);
    fill_kernel<<<N_EDGES / 256, 256, 0, stream>>>(row, col, disf, cursor, edat);

    const int gatherBlocks = N_NODES / 4;   // 12500

    // --- layer 1 ---
    gather_kernel<<<gatherBlocks, 256, 0, stream>>>(offs, cnt, edat, x, T1);
    gather_kernel<<<gatherBlocks, 256, 0, stream>>>(offs, cnt, edat, T1, T2);
    cheb_fused_kernel<<<gatherBlocks, 256, 0, stream>>>(x, T1, T2, W1, b1, H);

    // --- layer 2 ---
    gather_kernel<<<gatherBlocks, 256, 0, stream>>>(offs, cnt, edat, H, T1);
    gather_kernel<<<gatherBlocks, 256, 0, stream>>>(offs, cnt, edat, T1, T2);
    cheb_fused_kernel<<<gatherBlocks, 256, 0, stream>>>(H, T1, T2, W2, b2, H); // in-place safe

    // --- head ---
    logits_kernel<<<(N_NODES + 255) / 256, 256, 0, stream>>>(H, Wlin, blin, out);
    edgecopy_kernel<<<(2 * N_EDGES + 255) / 256, 256, 0, stream>>>(ei, out + (size_t)N_NODES * 2);
}

// Round 8
// 718.686 us; speedup vs baseline: 1.5809x; 1.5809x over previous
//
#include <hip/hip_runtime.h>
#include <hip/hip_bf16.h>

// Problem constants (from reference)
#define N_NODES 50000
#define N_EDGES 1600000
#define D_FEAT  64

// ---------------------------------------------------------------------------
// Kernel 1: out-degree histogram (over row) + in-degree histogram (over col)
// ---------------------------------------------------------------------------
__global__ void degcnt_kernel(const int* __restrict__ row, const int* __restrict__ col,
                              int* __restrict__ degi, int* __restrict__ cnt) {
    int e = blockIdx.x * blockDim.x + threadIdx.x;
    if (e < N_EDGES) {
        atomicAdd(&degi[row[e]], 1);
        atomicAdd(&cnt[col[e]], 1);
    }
}

// ---------------------------------------------------------------------------
// Kernel 2: dis[i] = deg>0 ? rsqrt(deg) : 0
// ---------------------------------------------------------------------------
__global__ void dis_kernel(const int* __restrict__ degi, float* __restrict__ disf) {
    int i = blockIdx.x * blockDim.x + threadIdx.x;
    if (i < N_NODES) {
        int d = degi[i];
        disf[i] = (d > 0) ? rsqrtf((float)d) : 0.0f;
    }
}

// ---------------------------------------------------------------------------
// Parallel scan, 3 kernels. 196 blocks x 256 = 50176 >= 50000.
// ---------------------------------------------------------------------------
__global__ void scanA_kernel(const int* __restrict__ cnt, int* __restrict__ bsum) {
    __shared__ int red[256];
    int t = threadIdx.x;
    int i = blockIdx.x * 256 + t;
    int v = (i < N_NODES) ? cnt[i] : 0;
    red[t] = v;
    __syncthreads();
    for (int d = 128; d > 0; d >>= 1) {
        if (t < d) red[t] += red[t + d];
        __syncthreads();
    }
    if (t == 0) bsum[blockIdx.x] = red[0];
}

__global__ void scanB_kernel(const int* __restrict__ bsum, int* __restrict__ bpre) {
    __shared__ int part[256];
    int t = threadIdx.x;
    int v = (t < 196) ? bsum[t] : 0;
    part[t] = v;
    __syncthreads();
    for (int d = 1; d < 256; d <<= 1) {
        int x = part[t];
        int a = (t >= d) ? part[t - d] : 0;
        __syncthreads();
        part[t] = x + a;
        __syncthreads();
    }
    if (t < 196) bpre[t] = part[t] - v;   // exclusive prefix of block sums
}

__global__ void scanC_kernel(const int* __restrict__ cnt, const int* __restrict__ bpre,
                             int* __restrict__ offs, int* __restrict__ cursor) {
    __shared__ int part[256];
    int t = threadIdx.x;
    int i = blockIdx.x * 256 + t;
    int v = (i < N_NODES) ? cnt[i] : 0;
    part[t] = v;
    __syncthreads();
    for (int d = 1; d < 256; d <<= 1) {
        int x = part[t];
        int a = (t >= d) ? part[t - d] : 0;
        __syncthreads();
        part[t] = x + a;
        __syncthreads();
    }
    if (i < N_NODES) {
        int off = bpre[blockIdx.x] + part[t] - v;   // global exclusive prefix
        offs[i] = off;
        cursor[i] = off;
    }
}

// ---------------------------------------------------------------------------
// Kernel 4: CSR fill — slot per edge grouped by target; stores src only (4B).
// Weight is recomputed during gather as dis[src] (and -dis[n] at the end).
// ---------------------------------------------------------------------------
__global__ void fill_kernel(const int* __restrict__ row, const int* __restrict__ col,
                            int* __restrict__ cursor, int* __restrict__ esrc) {
    int e = blockIdx.x * blockDim.x + threadIdx.x;
    if (e < N_EDGES) {
        int r = row[e];
        int c = col[e];
        int p = atomicAdd(&cursor[c], 1);
        esrc[p] = r;
    }
}

// ---------------------------------------------------------------------------
// Kernel 5: gather prop — out[n][j] = -dis[n] * sum_{e in in(n)} dis[src]*z[src][j]
// One wave per node, lane = feature. Unroll-by-8 with independent accumulators
// to get 8 outstanding row loads per wave (latency hiding / MLP).
// ---------------------------------------------------------------------------
__global__ __launch_bounds__(256) void gather_kernel(
        const int* __restrict__ offs, const int* __restrict__ cnt,
        const int* __restrict__ esrc, const float* __restrict__ dis,
        const float* __restrict__ z, float* __restrict__ out) {
    int t  = threadIdx.x;
    int wv = t >> 6;            // wave within block: 0..3
    int j  = t & 63;            // feature
    int n  = blockIdx.x * 4 + wv;   // 12500 * 4 = 50000 exact
    int start = offs[n];
    int m     = cnt[n];
    const int* ep = esrc + start;

    float a0 = 0.f, a1 = 0.f, a2 = 0.f, a3 = 0.f;
    float a4 = 0.f, a5 = 0.f, a6 = 0.f, a7 = 0.f;
    int k = 0;
    int m8 = m & ~7;
    for (; k < m8; k += 8) {
        int s0 = ep[k + 0], s1 = ep[k + 1], s2 = ep[k + 2], s3 = ep[k + 3];
        int s4 = ep[k + 4], s5 = ep[k + 5], s6 = ep[k + 6], s7 = ep[k + 7];
        float w0 = dis[s0], w1 = dis[s1], w2 = dis[s2], w3 = dis[s3];
        float w4 = dis[s4], w5 = dis[s5], w6 = dis[s6], w7 = dis[s7];
        a0 += w0 * z[(size_t)s0 * D_FEAT + j];
        a1 += w1 * z[(size_t)s1 * D_FEAT + j];
        a2 += w2 * z[(size_t)s2 * D_FEAT + j];
        a3 += w3 * z[(size_t)s3 * D_FEAT + j];
        a4 += w4 * z[(size_t)s4 * D_FEAT + j];
        a5 += w5 * z[(size_t)s5 * D_FEAT + j];
        a6 += w6 * z[(size_t)s6 * D_FEAT + j];
        a7 += w7 * z[(size_t)s7 * D_FEAT + j];
    }
    for (; k < m; ++k) {
        int s = ep[k];
        a0 += dis[s] * z[(size_t)s * D_FEAT + j];
    }
    float acc = ((a0 + a1) + (a2 + a3)) + ((a4 + a5) + (a6 + a7));
    out[(size_t)n * D_FEAT + j] = -dis[n] * acc;
}

// ---------------------------------------------------------------------------
// Kernel 6: fused Chebyshev combine + bias + relu
//   h[n] = relu( z[n]@(W0-W2) + t1[n]@W1 + 2*t2[n]@W2 + b )
// (Tx2 = 2*t2 - z;  out = z@W0 + t1@W1 + Tx2@W2)
// Block: 256 threads = 4 nodes x 64 output features. In-place safe (LDS
// staging of own rows before any write).
// ---------------------------------------------------------------------------
__global__ void cheb_fused_kernel(const float* __restrict__ z, const float* __restrict__ t1,
                                  const float* __restrict__ t2,
                                  const float* __restrict__ W, const float* __restrict__ b,
                                  float* __restrict__ h) {
    __shared__ float zs[4][D_FEAT];
    __shared__ float t1s[4][D_FEAT];
    __shared__ float t2s[4][D_FEAT];
    int t  = threadIdx.x;
    int nl = t >> 6;
    int j  = t & 63;
    int node = blockIdx.x * 4 + nl;
    size_t base = (size_t)node * D_FEAT + j;
    zs[nl][j]  = z[base];
    t1s[nl][j] = t1[base];
    t2s[nl][j] = t2[base];
    __syncthreads();

    const float* W0 = W;
    const float* W1 = W + D_FEAT * D_FEAT;
    const float* W2 = W + 2 * D_FEAT * D_FEAT;

    float acc = b[j];
    #pragma unroll
    for (int k = 0; k < D_FEAT; ++k) {
        float w2 = W2[k * D_FEAT + j];
        acc += zs[nl][k]  * (W0[k * D_FEAT + j] - w2);
        acc += t1s[nl][k] * W1[k * D_FEAT + j];
        acc += 2.0f * t2s[nl][k] * w2;
    }
    h[base] = fmaxf(acc, 0.0f);
}

// ---------------------------------------------------------------------------
// Kernel 7: logits[n] = h[n] @ Wlin + blin  (64 -> 2), float32 out
// ---------------------------------------------------------------------------
__global__ void logits_kernel(const float* __restrict__ h, const float* __restrict__ Wlin,
                              const float* __restrict__ blin,
                              float* __restrict__ out) {
    int n = blockIdx.x * blockDim.x + threadIdx.x;
    if (n >= N_NODES) return;
    float a0 = blin[0];
    float a1 = blin[1];
    const float4* hr = reinterpret_cast<const float4*>(h + (size_t)n * D_FEAT);
    #pragma unroll
    for (int q = 0; q < D_FEAT / 4; ++q) {
        float4 v = hr[q];
        int j = q * 4;
        a0 += v.x * Wlin[(j + 0) * 2] + v.y * Wlin[(j + 1) * 2]
            + v.z * Wlin[(j + 2) * 2] + v.w * Wlin[(j + 3) * 2];
        a1 += v.x * Wlin[(j + 0) * 2 + 1] + v.y * Wlin[(j + 1) * 2 + 1]
            + v.z * Wlin[(j + 2) * 2 + 1] + v.w * Wlin[(j + 3) * 2 + 1];
    }
    out[n * 2 + 0] = a0;
    out[n * 2 + 1] = a1;
}

// ---------------------------------------------------------------------------
// Kernel 8: echo edge_index into output (as float32)
// ---------------------------------------------------------------------------
__global__ void edgecopy_kernel(const int* __restrict__ ei, float* __restrict__ out) {
    int t = blockIdx.x * blockDim.x + threadIdx.x;
    if (t < 2 * N_EDGES) {
        out[t] = (float)ei[t];
    }
}

// ---------------------------------------------------------------------------
extern "C" void kernel_launch(void* const* d_in, const int* in_sizes, int n_in,
                              void* d_out, int out_size, void* d_ws, size_t ws_size,
                              hipStream_t stream) {
    const float* x    = (const float*)d_in[0];
    const int*   ei   = (const int*)d_in[1];
    const float* W1   = (const float*)d_in[2];
    const float* b1   = (const float*)d_in[3];
    const float* W2   = (const float*)d_in[4];
    const float* b2   = (const float*)d_in[5];
    const float* Wlin = (const float*)d_in[6];
    const float* blin = (const float*)d_in[7];
    float* out = (float*)d_out;      // float32 output buffer
    float* ws  = (float*)d_ws;

    const int* row = ei;             // edge_index[0] = source
    const int* col = ei + N_EDGES;   // edge_index[1] = target

    // workspace layout (4-byte units); total ~45.8 MB
    int*   degi   = (int*)ws;                     // [50176]
    float* disf   = ws + 50176;                   // [50176]
    int*   cnt    = (int*)(ws + 100352);          // [50176]
    int*   offs   = (int*)(ws + 150528);          // [50176]
    int*   cursor = (int*)(ws + 200704);          // [50176]
    int*   bsum   = (int*)(ws + 250880);          // [256]
    int*   bpre   = (int*)(ws + 251136);          // [256]
    int*   esrc   = (int*)(ws + 251392);          // [1600000]
    float* T1     = ws + 1851392;                 // [3.2M]
    float* T2     = ws + 5051392;                 // [3.2M]
    float* H      = ws + 8251392;                 // [3.2M]

    // --- CSR build ---
    hipMemsetAsync(degi, 0, N_NODES * sizeof(int), stream);
    hipMemsetAsync(cnt,  0, N_NODES * sizeof(int), stream);
    degcnt_kernel<<<N_EDGES / 256, 256, 0, stream>>>(row, col, degi, cnt);
    dis_kernel<<<(N_NODES + 255) / 256, 256, 0, stream>>>(degi, disf);
    scanA_kernel<<<196, 256, 0, stream>>>(cnt, bsum);
    scanB_kernel<<<1, 256, 0, stream>>>(bsum, bpre);
    scanC_kernel<<<196, 256, 0, stream>>>(cnt, bpre, offs, cursor);
    fill_kernel<<<N_EDGES / 256, 256, 0, stream>>>(row, col, cursor, esrc);

    const int gatherBlocks = N_NODES / 4;   // 12500

    // --- layer 1 ---
    gather_kernel<<<gatherBlocks, 256, 0, stream>>>(offs, cnt, esrc, disf, x, T1);
    gather_kernel<<<gatherBlocks, 256, 0, stream>>>(offs, cnt, esrc, disf, T1, T2);
    cheb_fused_kernel<<<gatherBlocks, 256, 0, stream>>>(x, T1, T2, W1, b1, H);

    // --- layer 2 ---
    gather_kernel<<<gatherBlocks, 256, 0, stream>>>(offs, cnt, esrc, disf, H, T1);
    gather_kernel<<<gatherBlocks, 256, 0, stream>>>(offs, cnt, esrc, disf, T1, T2);
    cheb_fused_kernel<<<gatherBlocks, 256, 0, stream>>>(H, T1, T2, W2, b2, H); // in-place safe

    // --- head ---
    logits_kernel<<<(N_NODES + 255) / 256, 256, 0, stream>>>(H, Wlin, blin, out);
    edgecopy_kernel<<<(2 * N_EDGES + 255) / 256, 256, 0, stream>>>(ei, out + (size_t)N_NODES * 2);
}

// Round 9
// 669.425 us; speedup vs baseline: 1.6973x; 1.0736x over previous
//
#include <hip/hip_runtime.h>
#include <hip/hip_bf16.h>

// Problem constants (from reference)
#define N_NODES 50000
#define N_EDGES 1600000
#define D_FEAT  64
#define NB      391          // coarse buckets: col>>7, max col 49999 -> bucket 390
#define TILE    4096         // edges per bin_kernel block

// ---------------------------------------------------------------------------
// Kernel 1: out-degree histogram (over row) + in-degree histogram (over col)
// ---------------------------------------------------------------------------
__global__ void degcnt_kernel(const int* __restrict__ row, const int* __restrict__ col,
                              int* __restrict__ degi, int* __restrict__ cnt) {
    int e = blockIdx.x * blockDim.x + threadIdx.x;
    if (e < N_EDGES) {
        atomicAdd(&degi[row[e]], 1);
        atomicAdd(&cnt[col[e]], 1);
    }
}

// ---------------------------------------------------------------------------
// Kernel 2: dis[i] = deg>0 ? rsqrt(deg) : 0
// ---------------------------------------------------------------------------
__global__ void dis_kernel(const int* __restrict__ degi, float* __restrict__ disf) {
    int i = blockIdx.x * blockDim.x + threadIdx.x;
    if (i < N_NODES) {
        int d = degi[i];
        disf[i] = (d > 0) ? rsqrtf((float)d) : 0.0f;
    }
}

// ---------------------------------------------------------------------------
// Parallel scan for per-node CSR offsets, 3 kernels. 196 blocks x 256.
// ---------------------------------------------------------------------------
__global__ void scanA_kernel(const int* __restrict__ cnt, int* __restrict__ bsum) {
    __shared__ int red[256];
    int t = threadIdx.x;
    int i = blockIdx.x * 256 + t;
    int v = (i < N_NODES) ? cnt[i] : 0;
    red[t] = v;
    __syncthreads();
    for (int d = 128; d > 0; d >>= 1) {
        if (t < d) red[t] += red[t + d];
        __syncthreads();
    }
    if (t == 0) bsum[blockIdx.x] = red[0];
}

__global__ void scanB_kernel(const int* __restrict__ bsum, int* __restrict__ bpre) {
    __shared__ int part[256];
    int t = threadIdx.x;
    int v = (t < 196) ? bsum[t] : 0;
    part[t] = v;
    __syncthreads();
    for (int d = 1; d < 256; d <<= 1) {
        int x = part[t];
        int a = (t >= d) ? part[t - d] : 0;
        __syncthreads();
        part[t] = x + a;
        __syncthreads();
    }
    if (t < 196) bpre[t] = part[t] - v;   // exclusive prefix of block sums
}

__global__ void scanC_kernel(const int* __restrict__ cnt, const int* __restrict__ bpre,
                             int* __restrict__ offs, int* __restrict__ cursor) {
    __shared__ int part[256];
    int t = threadIdx.x;
    int i = blockIdx.x * 256 + t;
    int v = (i < N_NODES) ? cnt[i] : 0;
    part[t] = v;
    __syncthreads();
    for (int d = 1; d < 256; d <<= 1) {
        int x = part[t];
        int a = (t >= d) ? part[t - d] : 0;
        __syncthreads();
        part[t] = x + a;
        __syncthreads();
    }
    if (i < N_NODES) {
        int off = bpre[blockIdx.x] + part[t] - v;   // global exclusive prefix
        offs[i] = off;
        cursor[i] = off;
    }
}

// ---------------------------------------------------------------------------
// Bucket scan: bucket b covers cols [b*128, b*128+128). Sums cnt directly
// (no per-edge atomics), exclusive-scans, writes bucket bases + cursors.
// One block, 512 threads.
// ---------------------------------------------------------------------------
__global__ void bscan_kernel(const int* __restrict__ cnt,
                             int* __restrict__ bbase, int* __restrict__ gcur) {
    __shared__ int part[512];
    int t = threadIdx.x;
    int s = 0;
    if (t < NB) {
        int lo = t << 7;
        int hi = lo + 128; if (hi > N_NODES) hi = N_NODES;
        for (int i = lo; i < hi; ++i) s += cnt[i];
    }
    part[t] = s;
    __syncthreads();
    for (int d = 1; d < 512; d <<= 1) {
        int x = part[t];
        int a = (t >= d) ? part[t - d] : 0;
        __syncthreads();
        part[t] = x + a;
        __syncthreads();
    }
    if (t < NB) {
        int off = part[t] - s;
        bbase[t] = off;
        gcur[t]  = off;
    }
    if (t == NB) bbase[NB] = N_EDGES;
}

// ---------------------------------------------------------------------------
// Phase 1: bin edges by coarse bucket (col>>7) into ebuf as (src, col).
// LDS histogram + one global reservation per (block,bucket) makes the
// scattered writes into ~NB sequential streams (~84B per advance).
// ---------------------------------------------------------------------------
__global__ __launch_bounds__(256) void bin_kernel(const int* __restrict__ row,
                                                  const int* __restrict__ col,
                                                  int* __restrict__ gcur,
                                                  int2* __restrict__ ebuf) {
    __shared__ int lcol[TILE];    // 16 KB
    __shared__ int lhist[NB];
    __shared__ int lcur[NB];
    int t = threadIdx.x;
    int base = blockIdx.x * TILE;
    int nEdge = N_EDGES - base; if (nEdge > TILE) nEdge = TILE;

    for (int i = t; i < NB; i += 256) lhist[i] = 0;
    for (int i = t; i < nEdge; i += 256) lcol[i] = col[base + i];
    __syncthreads();
    for (int i = t; i < nEdge; i += 256) atomicAdd(&lhist[lcol[i] >> 7], 1);
    __syncthreads();
    for (int i = t; i < NB; i += 256) {
        int h = lhist[i];
        lcur[i] = (h > 0) ? atomicAdd(&gcur[i], h) : 0;
    }
    __syncthreads();
    for (int i = t; i < nEdge; i += 256) {
        int c = lcol[i];
        int p = atomicAdd(&lcur[c >> 7], 1);
        ebuf[p] = make_int2(row[base + i], c);
    }
}

// ---------------------------------------------------------------------------
// Phase 2: fine CSR fill. Block b owns bucket b; its cursor atomics and
// esrc writes land in a ~16KB window -> single-writer L2 locality.
// ---------------------------------------------------------------------------
__global__ __launch_bounds__(256) void csr_fill_kernel(const int* __restrict__ bbase,
                                                       const int2* __restrict__ ebuf,
                                                       int* __restrict__ cursor,
                                                       int* __restrict__ esrc) {
    int b = blockIdx.x;
    int s = bbase[b], e2 = bbase[b + 1];
    for (int i = s + threadIdx.x; i < e2; i += 256) {
        int2 d = ebuf[i];
        int p = atomicAdd(&cursor[d.y], 1);
        esrc[p] = d.x;
    }
}

// ---------------------------------------------------------------------------
// Gather prop — out[n][j] = -dis[n] * sum_{e in in(n)} dis[src]*z[src][j]
// One wave per node, lane = feature, unroll-by-8 for MLP.
// ---------------------------------------------------------------------------
__global__ __launch_bounds__(256) void gather_kernel(
        const int* __restrict__ offs, const int* __restrict__ cnt,
        const int* __restrict__ esrc, const float* __restrict__ dis,
        const float* __restrict__ z, float* __restrict__ out) {
    int t  = threadIdx.x;
    int wv = t >> 6;            // wave within block: 0..3
    int j  = t & 63;            // feature
    int n  = blockIdx.x * 4 + wv;   // 12500 * 4 = 50000 exact
    int start = offs[n];
    int m     = cnt[n];
    const int* ep = esrc + start;

    float a0 = 0.f, a1 = 0.f, a2 = 0.f, a3 = 0.f;
    float a4 = 0.f, a5 = 0.f, a6 = 0.f, a7 = 0.f;
    int k = 0;
    int m8 = m & ~7;
    for (; k < m8; k += 8) {
        int s0 = ep[k + 0], s1 = ep[k + 1], s2 = ep[k + 2], s3 = ep[k + 3];
        int s4 = ep[k + 4], s5 = ep[k + 5], s6 = ep[k + 6], s7 = ep[k + 7];
        float w0 = dis[s0], w1 = dis[s1], w2 = dis[s2], w3 = dis[s3];
        float w4 = dis[s4], w5 = dis[s5], w6 = dis[s6], w7 = dis[s7];
        a0 += w0 * z[(size_t)s0 * D_FEAT + j];
        a1 += w1 * z[(size_t)s1 * D_FEAT + j];
        a2 += w2 * z[(size_t)s2 * D_FEAT + j];
        a3 += w3 * z[(size_t)s3 * D_FEAT + j];
        a4 += w4 * z[(size_t)s4 * D_FEAT + j];
        a5 += w5 * z[(size_t)s5 * D_FEAT + j];
        a6 += w6 * z[(size_t)s6 * D_FEAT + j];
        a7 += w7 * z[(size_t)s7 * D_FEAT + j];
    }
    for (; k < m; ++k) {
        int s = ep[k];
        a0 += dis[s] * z[(size_t)s * D_FEAT + j];
    }
    float acc = ((a0 + a1) + (a2 + a3)) + ((a4 + a5) + (a6 + a7));
    out[(size_t)n * D_FEAT + j] = -dis[n] * acc;
}

// ---------------------------------------------------------------------------
// Fused Chebyshev combine + bias + relu
//   h[n] = relu( z[n]@(W0-W2) + t1[n]@W1 + 2*t2[n]@W2 + b )
// ---------------------------------------------------------------------------
__global__ void cheb_fused_kernel(const float* __restrict__ z, const float* __restrict__ t1,
                                  const float* __restrict__ t2,
                                  const float* __restrict__ W, const float* __restrict__ b,
                                  float* __restrict__ h) {
    __shared__ float zs[4][D_FEAT];
    __shared__ float t1s[4][D_FEAT];
    __shared__ float t2s[4][D_FEAT];
    int t  = threadIdx.x;
    int nl = t >> 6;
    int j  = t & 63;
    int node = blockIdx.x * 4 + nl;
    size_t base = (size_t)node * D_FEAT + j;
    zs[nl][j]  = z[base];
    t1s[nl][j] = t1[base];
    t2s[nl][j] = t2[base];
    __syncthreads();

    const float* W0 = W;
    const float* W1 = W + D_FEAT * D_FEAT;
    const float* W2 = W + 2 * D_FEAT * D_FEAT;

    float acc = b[j];
    #pragma unroll
    for (int k = 0; k < D_FEAT; ++k) {
        float w2 = W2[k * D_FEAT + j];
        acc += zs[nl][k]  * (W0[k * D_FEAT + j] - w2);
        acc += t1s[nl][k] * W1[k * D_FEAT + j];
        acc += 2.0f * t2s[nl][k] * w2;
    }
    h[base] = fmaxf(acc, 0.0f);
}

// ---------------------------------------------------------------------------
// logits[n] = h[n] @ Wlin + blin  (64 -> 2), float32 out
// ---------------------------------------------------------------------------
__global__ void logits_kernel(const float* __restrict__ h, const float* __restrict__ Wlin,
                              const float* __restrict__ blin,
                              float* __restrict__ out) {
    int n = blockIdx.x * blockDim.x + threadIdx.x;
    if (n >= N_NODES) return;
    float a0 = blin[0];
    float a1 = blin[1];
    const float4* hr = reinterpret_cast<const float4*>(h + (size_t)n * D_FEAT);
    #pragma unroll
    for (int q = 0; q < D_FEAT / 4; ++q) {
        float4 v = hr[q];
        int j = q * 4;
        a0 += v.x * Wlin[(j + 0) * 2] + v.y * Wlin[(j + 1) * 2]
            + v.z * Wlin[(j + 2) * 2] + v.w * Wlin[(j + 3) * 2];
        a1 += v.x * Wlin[(j + 0) * 2 + 1] + v.y * Wlin[(j + 1) * 2 + 1]
            + v.z * Wlin[(j + 2) * 2 + 1] + v.w * Wlin[(j + 3) * 2 + 1];
    }
    out[n * 2 + 0] = a0;
    out[n * 2 + 1] = a1;
}

// ---------------------------------------------------------------------------
// echo edge_index into output (as float32)
// ---------------------------------------------------------------------------
__global__ void edgecopy_kernel(const int* __restrict__ ei, float* __restrict__ out) {
    int t = blockIdx.x * blockDim.x + threadIdx.x;
    if (t < 2 * N_EDGES) {
        out[t] = (float)ei[t];
    }
}

// ---------------------------------------------------------------------------
extern "C" void kernel_launch(void* const* d_in, const int* in_sizes, int n_in,
                              void* d_out, int out_size, void* d_ws, size_t ws_size,
                              hipStream_t stream) {
    const float* x    = (const float*)d_in[0];
    const int*   ei   = (const int*)d_in[1];
    const float* W1   = (const float*)d_in[2];
    const float* b1   = (const float*)d_in[3];
    const float* W2   = (const float*)d_in[4];
    const float* b2   = (const float*)d_in[5];
    const float* Wlin = (const float*)d_in[6];
    const float* blin = (const float*)d_in[7];
    float* out = (float*)d_out;      // float32 output buffer
    float* ws  = (float*)d_ws;

    const int* row = ei;             // edge_index[0] = source
    const int* col = ei + N_EDGES;   // edge_index[1] = target

    // workspace layout (4-byte units); total ~45.8 MB
    int*   degi   = (int*)ws;                     // [50176]
    float* disf   = ws + 50176;                   // [50176]
    int*   cnt    = (int*)(ws + 100352);          // [50176]
    int*   offs   = (int*)(ws + 150528);          // [50176]
    int*   cursor = (int*)(ws + 200704);          // [50176]
    int*   bsum   = (int*)(ws + 250880);          // [256]
    int*   bpre   = (int*)(ws + 251136);          // [256]
    int*   bbase  = (int*)(ws + 251392);          // [512] (NB+1 used)
    int*   gcur   = (int*)(ws + 251904);          // [512]
    int*   esrc   = (int*)(ws + 252416);          // [1600000]
    float* T1     = ws + 1852416;                 // [3.2M]
    float* T2     = ws + 5052416;                 // [3.2M]  (8B-aligned offset)
    float* H      = ws + 8252416;                 // [3.2M]
    int2*  ebuf   = (int2*)T2;                    // aliases T2: live only bin->csr_fill

    // --- CSR build ---
    hipMemsetAsync(degi, 0, N_NODES * sizeof(int), stream);
    hipMemsetAsync(cnt,  0, N_NODES * sizeof(int), stream);
    degcnt_kernel<<<N_EDGES / 256, 256, 0, stream>>>(row, col, degi, cnt);
    dis_kernel<<<(N_NODES + 255) / 256, 256, 0, stream>>>(degi, disf);
    scanA_kernel<<<196, 256, 0, stream>>>(cnt, bsum);
    scanB_kernel<<<1, 256, 0, stream>>>(bsum, bpre);
    scanC_kernel<<<196, 256, 0, stream>>>(cnt, bpre, offs, cursor);
    bscan_kernel<<<1, 512, 0, stream>>>(cnt, bbase, gcur);
    bin_kernel<<<(N_EDGES + TILE - 1) / TILE, 256, 0, stream>>>(row, col, gcur, ebuf);
    csr_fill_kernel<<<NB, 256, 0, stream>>>(bbase, ebuf, cursor, esrc);

    const int gatherBlocks = N_NODES / 4;   // 12500

    // --- layer 1 ---
    gather_kernel<<<gatherBlocks, 256, 0, stream>>>(offs, cnt, esrc, disf, x, T1);
    gather_kernel<<<gatherBlocks, 256, 0, stream>>>(offs, cnt, esrc, disf, T1, T2);
    cheb_fused_kernel<<<gatherBlocks, 256, 0, stream>>>(x, T1, T2, W1, b1, H);

    // --- layer 2 ---
    gather_kernel<<<gatherBlocks, 256, 0, stream>>>(offs, cnt, esrc, disf, H, T1);
    gather_kernel<<<gatherBlocks, 256, 0, stream>>>(offs, cnt, esrc, disf, T1, T2);
    cheb_fused_kernel<<<gatherBlocks, 256, 0, stream>>>(H, T1, T2, W2, b2, H); // in-place safe

    // --- head ---
    logits_kernel<<<(N_NODES + 255) / 256, 256, 0, stream>>>(H, Wlin, blin, out);
    edgecopy_kernel<<<(2 * N_EDGES + 255) / 256, 256, 0, stream>>>(ei, out + (size_t)N_NODES * 2);
}

// Round 11
// 527.707 us; speedup vs baseline: 2.1531x; 1.2686x over previous
//
#include <hip/hip_runtime.h>
#include <hip/hip_bf16.h>

// Problem constants (from reference)
#define N_NODES 50000
#define N_EDGES 1600000
#define D_FEAT  64
#define NB      391          // coarse buckets: id>>7, max id 49999 -> bucket 390
#define TILE    4096         // edges per binning block
#define NBLK    391          // ceil(N_EDGES / TILE)

// ---------------------------------------------------------------------------
// Bucket histograms for col and row (LDS-privatized; tiny global footprint)
// ---------------------------------------------------------------------------
__global__ __launch_bounds__(256) void bhist_kernel(const int* __restrict__ row,
                                                    const int* __restrict__ col,
                                                    int* __restrict__ chist,
                                                    int* __restrict__ rhist) {
    __shared__ int hc[NB], hr[NB];
    int t = threadIdx.x;
    int base = blockIdx.x * TILE;
    int n = N_EDGES - base; if (n > TILE) n = TILE;
    for (int i = t; i < NB; i += 256) { hc[i] = 0; hr[i] = 0; }
    __syncthreads();
    for (int i = t; i < n; i += 256) {
        atomicAdd(&hc[col[base + i] >> 7], 1);
        atomicAdd(&hr[row[base + i] >> 7], 1);
    }
    __syncthreads();
    for (int i = t; i < NB; i += 256) {
        if (hc[i]) atomicAdd(&chist[i], hc[i]);
        if (hr[i]) atomicAdd(&rhist[i], hr[i]);
    }
}

// ---------------------------------------------------------------------------
// Exclusive scan of both bucket histograms -> bases + cursors. 1 block.
// ---------------------------------------------------------------------------
__global__ void bucketscan_kernel(const int* __restrict__ chist, const int* __restrict__ rhist,
                                  int* __restrict__ cbase, int* __restrict__ ccur,
                                  int* __restrict__ rbase, int* __restrict__ rcur) {
    __shared__ int pc[512], pr[512];
    int t = threadIdx.x;
    int vc = (t < NB) ? chist[t] : 0;
    int vr = (t < NB) ? rhist[t] : 0;
    pc[t] = vc; pr[t] = vr;
    __syncthreads();
    for (int d = 1; d < 512; d <<= 1) {
        int xc = pc[t], xr = pr[t];
        int ac = (t >= d) ? pc[t - d] : 0;
        int ar = (t >= d) ? pr[t - d] : 0;
        __syncthreads();
        pc[t] = xc + ac; pr[t] = xr + ar;
        __syncthreads();
    }
    if (t < NB) {
        cbase[t] = pc[t] - vc; ccur[t] = pc[t] - vc;
        rbase[t] = pr[t] - vr; rcur[t] = pr[t] - vr;
    }
    if (t == NB) { cbase[NB] = N_EDGES; rbase[NB] = N_EDGES; }
}

// ---------------------------------------------------------------------------
// Bin edges: (src,col) by col-bucket into ebufC; row by row-bucket into rbuf.
// LDS hist + one global reservation per (block,bucket) -> sequential streams.
// ---------------------------------------------------------------------------
__global__ __launch_bounds__(256) void bin_both_kernel(const int* __restrict__ row,
                                                       const int* __restrict__ col,
                                                       int* __restrict__ ccur, int* __restrict__ rcur,
                                                       int2* __restrict__ ebufC, int* __restrict__ rbuf) {
    __shared__ int lrow[TILE];   // 16 KB
    __shared__ int lcol[TILE];   // 16 KB
    __shared__ int hc[NB], hr[NB], cc[NB], cr[NB];
    int t = threadIdx.x;
    int base = blockIdx.x * TILE;
    int n = N_EDGES - base; if (n > TILE) n = TILE;
    for (int i = t; i < NB; i += 256) { hc[i] = 0; hr[i] = 0; }
    for (int i = t; i < n; i += 256) { lrow[i] = row[base + i]; lcol[i] = col[base + i]; }
    __syncthreads();
    for (int i = t; i < n; i += 256) {
        atomicAdd(&hc[lcol[i] >> 7], 1);
        atomicAdd(&hr[lrow[i] >> 7], 1);
    }
    __syncthreads();
    for (int i = t; i < NB; i += 256) {
        cc[i] = hc[i] ? atomicAdd(&ccur[i], hc[i]) : 0;
        cr[i] = hr[i] ? atomicAdd(&rcur[i], hr[i]) : 0;
    }
    __syncthreads();
    for (int i = t; i < n; i += 256) {
        int c = lcol[i], r = lrow[i];
        int p = atomicAdd(&cc[c >> 7], 1);
        ebufC[p] = make_int2(r, c);
        int q = atomicAdd(&cr[r >> 7], 1);
        rbuf[q] = r;
    }
}

// ---------------------------------------------------------------------------
// Per-bucket CSR: LDS 128-hist -> cnt/offs (local scan), then place esrc via
// LDS cursors. All scattered traffic confined to the bucket's ~16KB window.
// ---------------------------------------------------------------------------
__global__ __launch_bounds__(256) void csr_bucket_kernel(const int* __restrict__ cbase,
                                                         const int2* __restrict__ ebufC,
                                                         int* __restrict__ cnt, int* __restrict__ offs,
                                                         int* __restrict__ esrc) {
    __shared__ int hist[128];
    __shared__ int pre[256];
    __shared__ int cur[128];
    int b = blockIdx.x, t = threadIdx.x;
    int s = cbase[b], e = cbase[b + 1];
    if (t < 128) hist[t] = 0;
    __syncthreads();
    for (int i = s + t; i < e; i += 256) atomicAdd(&hist[ebufC[i].y & 127], 1);
    __syncthreads();
    int v = (t < 128) ? hist[t] : 0;
    pre[t] = v;
    __syncthreads();
    for (int d = 1; d < 128; d <<= 1) {
        int x = pre[t];
        int a = (t >= d) ? pre[t - d] : 0;
        __syncthreads();
        pre[t] = x + a;
        __syncthreads();
    }
    if (t < 128) {
        int node = (b << 7) + t;
        if (node < N_NODES) {
            int off = s + pre[t] - v;
            cnt[node] = v;
            offs[node] = off;
            cur[t] = off;
        }
    }
    __syncthreads();
    for (int i = s + t; i < e; i += 256) {
        int2 d2 = ebufC[i];
        int p = atomicAdd(&cur[d2.y & 127], 1);
        esrc[p] = d2.x;
    }
}

// ---------------------------------------------------------------------------
// Per-bucket out-degree -> disf = rsqrt(deg) (replaces degcnt row-half + dis)
// ---------------------------------------------------------------------------
__global__ __launch_bounds__(256) void deg_bucket_kernel(const int* __restrict__ rbase,
                                                         const int* __restrict__ rbuf,
                                                         float* __restrict__ disf) {
    __shared__ int hist[128];
    int b = blockIdx.x, t = threadIdx.x;
    int s = rbase[b], e = rbase[b + 1];
    if (t < 128) hist[t] = 0;
    __syncthreads();
    for (int i = s + t; i < e; i += 256) atomicAdd(&hist[rbuf[i] & 127], 1);
    __syncthreads();
    if (t < 128) {
        int node = (b << 7) + t;
        if (node < N_NODES) {
            int d = hist[t];
            disf[node] = (d > 0) ? rsqrtf((float)d) : 0.0f;
        }
    }
}

// ---------------------------------------------------------------------------
// Gather prop — out[n][j] = -dis[n] * sum_{e in in(n)} dis[src]*z[src][j]
// One wave per node, lane = feature, unroll-by-8 for MLP.
// ---------------------------------------------------------------------------
__global__ __launch_bounds__(256) void gather_kernel(
        const int* __restrict__ offs, const int* __restrict__ cnt,
        const int* __restrict__ esrc, const float* __restrict__ dis,
        const float* __restrict__ z, float* __restrict__ out) {
    int t  = threadIdx.x;
    int wv = t >> 6;            // wave within block: 0..3
    int j  = t & 63;            // feature
    int n  = blockIdx.x * 4 + wv;   // 12500 * 4 = 50000 exact
    int start = offs[n];
    int m     = cnt[n];
    const int* ep = esrc + start;

    float a0 = 0.f, a1 = 0.f, a2 = 0.f, a3 = 0.f;
    float a4 = 0.f, a5 = 0.f, a6 = 0.f, a7 = 0.f;
    int k = 0;
    int m8 = m & ~7;
    for (; k < m8; k += 8) {
        int s0 = ep[k + 0], s1 = ep[k + 1], s2 = ep[k + 2], s3 = ep[k + 3];
        int s4 = ep[k + 4], s5 = ep[k + 5], s6 = ep[k + 6], s7 = ep[k + 7];
        float w0 = dis[s0], w1 = dis[s1], w2 = dis[s2], w3 = dis[s3];
        float w4 = dis[s4], w5 = dis[s5], w6 = dis[s6], w7 = dis[s7];
        a0 += w0 * z[(size_t)s0 * D_FEAT + j];
        a1 += w1 * z[(size_t)s1 * D_FEAT + j];
        a2 += w2 * z[(size_t)s2 * D_FEAT + j];
        a3 += w3 * z[(size_t)s3 * D_FEAT + j];
        a4 += w4 * z[(size_t)s4 * D_FEAT + j];
        a5 += w5 * z[(size_t)s5 * D_FEAT + j];
        a6 += w6 * z[(size_t)s6 * D_FEAT + j];
        a7 += w7 * z[(size_t)s7 * D_FEAT + j];
    }
    for (; k < m; ++k) {
        int s = ep[k];
        a0 += dis[s] * z[(size_t)s * D_FEAT + j];
    }
    float acc = ((a0 + a1) + (a2 + a3)) + ((a4 + a5) + (a6 + a7));
    out[(size_t)n * D_FEAT + j] = -dis[n] * acc;
}

// ---------------------------------------------------------------------------
// Fused Chebyshev combine + bias + relu
//   h[n] = relu( z[n]@(W0-W2) + t1[n]@W1 + 2*t2[n]@W2 + b )
// ---------------------------------------------------------------------------
__global__ void cheb_fused_kernel(const float* __restrict__ z, const float* __restrict__ t1,
                                  const float* __restrict__ t2,
                                  const float* __restrict__ W, const float* __restrict__ b,
                                  float* __restrict__ h) {
    __shared__ float zs[4][D_FEAT];
    __shared__ float t1s[4][D_FEAT];
    __shared__ float t2s[4][D_FEAT];
    int t  = threadIdx.x;
    int nl = t >> 6;
    int j  = t & 63;
    int node = blockIdx.x * 4 + nl;
    size_t base = (size_t)node * D_FEAT + j;
    zs[nl][j]  = z[base];
    t1s[nl][j] = t1[base];
    t2s[nl][j] = t2[base];
    __syncthreads();

    const float* W0 = W;
    const float* W1 = W + D_FEAT * D_FEAT;
    const float* W2 = W + 2 * D_FEAT * D_FEAT;

    float acc = b[j];
    #pragma unroll
    for (int k = 0; k < D_FEAT; ++k) {
        float w2 = W2[k * D_FEAT + j];
        acc += zs[nl][k]  * (W0[k * D_FEAT + j] - w2);
        acc += t1s[nl][k] * W1[k * D_FEAT + j];
        acc += 2.0f * t2s[nl][k] * w2;
    }
    h[base] = fmaxf(acc, 0.0f);
}

// ---------------------------------------------------------------------------
// logits[n] = h[n] @ Wlin + blin  (64 -> 2), float32 out
// ---------------------------------------------------------------------------
__global__ void logits_kernel(const float* __restrict__ h, const float* __restrict__ Wlin,
                              const float* __restrict__ blin,
                              float* __restrict__ out) {
    int n = blockIdx.x * blockDim.x + threadIdx.x;
    if (n >= N_NODES) return;
    float a0 = blin[0];
    float a1 = blin[1];
    const float4* hr = reinterpret_cast<const float4*>(h + (size_t)n * D_FEAT);
    #pragma unroll
    for (int q = 0; q < D_FEAT / 4; ++q) {
        float4 v = hr[q];
        int j = q * 4;
        a0 += v.x * Wlin[(j + 0) * 2] + v.y * Wlin[(j + 1) * 2]
            + v.z * Wlin[(j + 2) * 2] + v.w * Wlin[(j + 3) * 2];
        a1 += v.x * Wlin[(j + 0) * 2 + 1] + v.y * Wlin[(j + 1) * 2 + 1]
            + v.z * Wlin[(j + 2) * 2 + 1] + v.w * Wlin[(j + 3) * 2 + 1];
    }
    out[n * 2 + 0] = a0;
    out[n * 2 + 1] = a1;
}

// ---------------------------------------------------------------------------
// echo edge_index into output (as float32)
// ---------------------------------------------------------------------------
__global__ void edgecopy_kernel(const int* __restrict__ ei, float* __restrict__ out) {
    int t = blockIdx.x * blockDim.x + threadIdx.x;
    if (t < 2 * N_EDGES) {
        out[t] = (float)ei[t];
    }
}

// ---------------------------------------------------------------------------
extern "C" void kernel_launch(void* const* d_in, const int* in_sizes, int n_in,
                              void* d_out, int out_size, void* d_ws, size_t ws_size,
                              hipStream_t stream) {
    const float* x    = (const float*)d_in[0];
    const int*   ei   = (const int*)d_in[1];
    const float* W1   = (const float*)d_in[2];
    const float* b1   = (const float*)d_in[3];
    const float* W2   = (const float*)d_in[4];
    const float* b2   = (const float*)d_in[5];
    const float* Wlin = (const float*)d_in[6];
    const float* blin = (const float*)d_in[7];
    float* out = (float*)d_out;      // float32 output buffer
    float* ws  = (float*)d_ws;

    const int* row = ei;             // edge_index[0] = source
    const int* col = ei + N_EDGES;   // edge_index[1] = target

    // workspace layout (4-byte units); total ~45.4 MB
    float* disf   = ws;                           // [50176]
    int*   cnt    = (int*)(ws + 50176);           // [50176]
    int*   offs   = (int*)(ws + 100352);          // [50176]
    int*   chist  = (int*)(ws + 150528);          // [512]
    int*   rhist  = (int*)(ws + 151040);          // [512]
    int*   cbase  = (int*)(ws + 151552);          // [512]
    int*   ccur   = (int*)(ws + 152064);          // [512]
    int*   rbase  = (int*)(ws + 152576);          // [512]
    int*   rcur   = (int*)(ws + 153088);          // [512]
    int*   esrc   = (int*)(ws + 153600);          // [1600000]
    float* T1     = ws + 1753600;                 // [3.2M]
    float* T2     = ws + 4953600;                 // [3.2M]
    float* H      = ws + 8153600;                 // [3.2M]
    int*   rbuf   = (int*)T1;                     // aliases T1 (dead before gathers)
    int2*  ebufC  = (int2*)T2;                    // aliases T2 (byte offset % 8 == 0)

    // --- CSR build (no global scattered atomics) ---
    hipMemsetAsync(chist, 0, 1024 * sizeof(int), stream);   // chist + rhist
    bhist_kernel<<<NBLK, 256, 0, stream>>>(row, col, chist, rhist);
    bucketscan_kernel<<<1, 512, 0, stream>>>(chist, rhist, cbase, ccur, rbase, rcur);
    bin_both_kernel<<<NBLK, 256, 0, stream>>>(row, col, ccur, rcur, ebufC, rbuf);
    csr_bucket_kernel<<<NB, 256, 0, stream>>>(cbase, ebufC, cnt, offs, esrc);
    deg_bucket_kernel<<<NB, 256, 0, stream>>>(rbase, rbuf, disf);

    const int gatherBlocks = N_NODES / 4;   // 12500

    // --- layer 1 ---
    gather_kernel<<<gatherBlocks, 256, 0, stream>>>(offs, cnt, esrc, disf, x, T1);
    gather_kernel<<<gatherBlocks, 256, 0, stream>>>(offs, cnt, esrc, disf, T1, T2);
    cheb_fused_kernel<<<gatherBlocks, 256, 0, stream>>>(x, T1, T2, W1, b1, H);

    // --- layer 2 ---
    gather_kernel<<<gatherBlocks, 256, 0, stream>>>(offs, cnt, esrc, disf, H, T1);
    gather_kernel<<<gatherBlocks, 256, 0, stream>>>(offs, cnt, esrc, disf, T1, T2);
    cheb_fused_kernel<<<gatherBlocks, 256, 0, stream>>>(H, T1, T2, W2, b2, H); // in-place safe

    // --- head ---
    logits_kernel<<<(N_NODES + 255) / 256, 256, 0, stream>>>(H, Wlin, blin, out);
    edgecopy_kernel<<<(2 * N_EDGES + 255) / 256, 256, 0, stream>>>(ei, out + (size_t)N_NODES * 2);
}